// Round 1
// baseline (208.268 us; speedup 1.0000x reference)
//
#include <hip/hip_runtime.h>

// FWEnergyGAD: element-wise double-well energy + forces + GAD direction +
// 2x2 Hessian eigendecomposition (closed form).
//
// Outputs concatenated flat in return order (n = B):
//   [0,     n)   energy
//   [n,    3n)   forces      (B,2)
//   [3n,   5n)   energy_grad (B,2)
//   [5n,   9n)   hessian     (B,2,2)
//   [9n,  10n)   eigenval 0  (smaller)
//   [10n, 11n)   eigenval 1  (larger)
//
// v2: pure-streaming rework. Timed region = harness poison-fill (~110us,
// fixed) + kernel. Kernel was ~88us for 218 MB of traffic (2.5 TB/s eff).
// Changes: (a) all outputs via __builtin_nontemporal_store (output is
// write-once/never-read; avoid L2 allocate / write-allocate fetches),
// (b) 2 points per thread in split-half layout (i and i+n/2) so every
// load/store instruction stays unit-stride fully coalesced while doubling
// per-wave memory ILP, (c) branchless selects for the eigvec branch and
// the GAD normalization mask.

typedef float f2v __attribute__((ext_vector_type(2)));
typedef float f4v __attribute__((ext_vector_type(4)));

namespace {

__device__ __forceinline__ f2v mk2(float a, float b) {
    f2v r; r.x = a; r.y = b; return r;
}
__device__ __forceinline__ f4v mk4(float a, float b, float c, float d) {
    f4v r; r.x = a; r.y = b; r.z = c; r.w = d; return r;
}

struct PointOut {
    float e, fx, fy, gx, gy, hxx, hyy, l0, l1;
};

__device__ __forceinline__ PointOut compute_point(float px, float py) {
    const float BETA = 0.1f;
    PointOut o;
    float u = px - 0.5f;
    float v = py - 0.5f;
    float uu = u * u;
    float vv = v * v;
    float a = uu - 1.0f;   // u^2 - 1
    float b = vv - 1.0f;   // v^2 - 1

    o.e = a * a + b * b + BETA * u * v;

    float gx = 4.0f * u * a + BETA * v;
    float gy = 4.0f * v * b + BETA * u;
    o.fx = -gx;
    o.fy = -gy;

    o.hxx = 12.0f * uu - 4.0f;
    o.hyy = 12.0f * vv - 4.0f;
    // hxy = BETA (constant)

    // 2x2 symmetric eigendecomposition, closed form.
    float d = 0.5f * (o.hxx - o.hyy);
    float m = 0.5f * (o.hxx + o.hyy);
    float r = sqrtf(d * d + BETA * BETA);   // r >= 0.1, never degenerate
    o.l0 = m - r;                            // smaller eigenvalue
    o.l1 = m + r;                            // larger eigenvalue

    // Eigenvector of l0; branch (as select) chosen to avoid cancellation
    // (|d| can be ~380 vs hxy=0.1; the other branch computes r-|d| which is
    // catastrophic in fp32).
    bool pos = (d >= 0.0f);
    float wx = pos ? BETA : (d - r);
    float wy = pos ? -(d + r) : BETA;
    float n2 = wx * wx + wy * wy;            // >= 0.01

    // gad = -f + 2 (f.w_hat) w_hat ; sign of w irrelevant (quadratic).
    float fd = o.fx * wx + o.fy * wy;
    float s = 2.0f * fd / n2;
    float gadx = -o.fx + s * wx;
    float gady = -o.fy + s * wy;

    float prod = o.l0 * o.l1;                // matches reference's product
    float gmag = sqrtf(gadx * gadx + gady * gady);
    float scale = (prod > 0.0f && gmag < 1.0f)
                      ? (1.0f / fmaxf(gmag, 1e-30f))
                      : 1.0f;
    // TAU = 1.0 -> energy_grad == gad
    o.gx = gadx * scale;
    o.gy = gady * scale;
    return o;
}

}  // namespace

__global__ __launch_bounds__(256) void fw_energy_gad_kernel(
    const f2v* __restrict__ in, float* __restrict__ out, int n) {
    const float BETA = 0.1f;
    int half = n >> 1;
    size_t N = (size_t)n;
    size_t H = (size_t)half;

    float* e_out  = out;
    f2v*   f_out  = (f2v*)(out + N);
    f2v*   g_out  = (f2v*)(out + 3 * N);
    f4v*   h_out  = (f4v*)(out + 5 * N);
    float* l0_out = out + 9 * N;
    float* l1_out = out + 10 * N;

    int i = blockIdx.x * blockDim.x + threadIdx.x;
    if (i < half) {
        // Split-half pair: element i and element i + n/2. Every memory
        // instruction below is unit-stride across the wave.
        f2v p0 = in[i];
        f2v p1 = in[i + H];
        PointOut o0 = compute_point(p0.x, p0.y);
        PointOut o1 = compute_point(p1.x, p1.y);

        __builtin_nontemporal_store(o0.e, e_out + i);
        __builtin_nontemporal_store(o1.e, e_out + i + H);
        __builtin_nontemporal_store(mk2(o0.fx, o0.fy), f_out + i);
        __builtin_nontemporal_store(mk2(o1.fx, o1.fy), f_out + i + H);
        __builtin_nontemporal_store(mk2(o0.gx, o0.gy), g_out + i);
        __builtin_nontemporal_store(mk2(o1.gx, o1.gy), g_out + i + H);
        __builtin_nontemporal_store(mk4(o0.hxx, BETA, BETA, o0.hyy), h_out + i);
        __builtin_nontemporal_store(mk4(o1.hxx, BETA, BETA, o1.hyy), h_out + i + H);
        __builtin_nontemporal_store(o0.l0, l0_out + i);
        __builtin_nontemporal_store(o1.l0, l0_out + i + H);
        __builtin_nontemporal_store(o0.l1, l1_out + i);
        __builtin_nontemporal_store(o1.l1, l1_out + i + H);
    }

    // Odd-n tail (B = 4194304 is even; kept for safety).
    if ((n & 1) && blockIdx.x == 0 && threadIdx.x == 0) {
        int j = n - 1;
        f2v p = in[j];
        PointOut o = compute_point(p.x, p.y);
        e_out[j]  = o.e;
        f_out[j]  = mk2(o.fx, o.fy);
        g_out[j]  = mk2(o.gx, o.gy);
        h_out[j]  = mk4(o.hxx, BETA, BETA, o.hyy);
        l0_out[j] = o.l0;
        l1_out[j] = o.l1;
    }
}

extern "C" void kernel_launch(void* const* d_in, const int* in_sizes, int n_in,
                              void* d_out, int out_size, void* d_ws, size_t ws_size,
                              hipStream_t stream) {
    const f2v* in = (const f2v*)d_in[0];
    float* out = (float*)d_out;
    int n = in_sizes[0] / 2;   // B elements, each (x, y)

    int half = n >> 1;
    int block = 256;
    int grid = (half + block - 1) / block;
    if (grid < 1) grid = 1;
    fw_energy_gad_kernel<<<grid, block, 0, stream>>>(in, out, n);
}

// Round 2
// 206.093 us; speedup vs baseline: 1.0106x; 1.0106x over previous
//
#include <hip/hip_runtime.h>

// FWEnergyGAD: element-wise double-well energy + forces + GAD direction +
// 2x2 Hessian eigendecomposition (closed form).
//
// Outputs concatenated flat in return order (n = B):
//   [0,     n)   energy
//   [n,    3n)   forces      (B,2)
//   [3n,   5n)   energy_grad (B,2)
//   [5n,   9n)   hessian     (B,2,2)
//   [9n,  10n)   eigenval 0  (smaller)
//   [10n, 11n)   eigenval 1  (larger)
//
// v3: adjacent-quad streaming. v1 (1pt/thread) ran ~88us for 218 MB
// (2.5 TB/s eff) while the harness's own fill hits 6.6 TB/s in the same
// timed region -> the gap is store-stream burst locality, not ALU and not
// line-partiality. v2 (split-half + NT stores) regressed: split-half
// doubled the per-wave stream count to 12. v3 instead processes FOUR
// ADJACENT points per thread: per-wave bursts per stream grow to
// 0.5-4 KB contiguous, wave count drops 4x, 11 dwordx4 stores in flight
// per thread, still exactly 6 output streams per wave. Plain cached
// stores (NT regressed). Branchless selects kept.

typedef float f4v __attribute__((ext_vector_type(4)));

namespace {

__device__ __forceinline__ f4v mk4(float a, float b, float c, float d) {
    f4v r; r.x = a; r.y = b; r.z = c; r.w = d; return r;
}

struct PointOut {
    float e, fx, fy, gx, gy, hxx, hyy, l0, l1;
};

__device__ __forceinline__ PointOut compute_point(float px, float py) {
    const float BETA = 0.1f;
    PointOut o;
    float u = px - 0.5f;
    float v = py - 0.5f;
    float uu = u * u;
    float vv = v * v;
    float a = uu - 1.0f;   // u^2 - 1
    float b = vv - 1.0f;   // v^2 - 1

    o.e = a * a + b * b + BETA * u * v;

    float gx = 4.0f * u * a + BETA * v;
    float gy = 4.0f * v * b + BETA * u;
    o.fx = -gx;
    o.fy = -gy;

    o.hxx = 12.0f * uu - 4.0f;
    o.hyy = 12.0f * vv - 4.0f;
    // hxy = BETA (constant)

    // 2x2 symmetric eigendecomposition, closed form.
    float d = 0.5f * (o.hxx - o.hyy);
    float m = 0.5f * (o.hxx + o.hyy);
    float r = sqrtf(d * d + BETA * BETA);   // r >= 0.1, never degenerate
    o.l0 = m - r;                            // smaller eigenvalue
    o.l1 = m + r;                            // larger eigenvalue

    // Eigenvector of l0; select-branch chosen to avoid cancellation
    // (|d| can be ~380 vs hxy=0.1; the wrong branch computes r-|d|,
    // catastrophic in fp32).
    bool pos = (d >= 0.0f);
    float wx = pos ? BETA : (d - r);
    float wy = pos ? -(d + r) : BETA;
    float n2 = wx * wx + wy * wy;            // >= 0.01

    // gad = -f + 2 (f.w_hat) w_hat ; sign of w irrelevant (quadratic).
    float fd = o.fx * wx + o.fy * wy;
    float s = 2.0f * fd / n2;
    float gadx = -o.fx + s * wx;
    float gady = -o.fy + s * wy;

    float prod = o.l0 * o.l1;                // matches reference's product
    float gmag = sqrtf(gadx * gadx + gady * gady);
    float scale = (prod > 0.0f && gmag < 1.0f)
                      ? (1.0f / fmaxf(gmag, 1e-30f))
                      : 1.0f;
    // TAU = 1.0 -> energy_grad == gad
    o.gx = gadx * scale;
    o.gy = gady * scale;
    return o;
}

}  // namespace

__global__ __launch_bounds__(256) void fw_energy_gad_kernel(
    const f4v* __restrict__ in4, float* __restrict__ out, int n) {
    const float BETA = 0.1f;
    size_t N = (size_t)n;
    int nq = n >> 2;           // number of point-quads

    float* e_out  = out;
    float* f_out  = out + N;
    float* g_out  = out + 3 * N;
    float* h_out  = out + 5 * N;
    float* l0_out = out + 9 * N;
    float* l1_out = out + 10 * N;

    int t = blockIdx.x * blockDim.x + threadIdx.x;   // quad index
    if (t < nq) {
        // Points 4t .. 4t+3 (adjacent). Input: two float4 loads = 4 float2.
        f4v pa = in4[(size_t)2 * t];
        f4v pb = in4[(size_t)2 * t + 1];
        PointOut o0 = compute_point(pa.x, pa.y);
        PointOut o1 = compute_point(pa.z, pa.w);
        PointOut o2 = compute_point(pb.x, pb.y);
        PointOut o3 = compute_point(pb.z, pb.w);

        size_t t4 = (size_t)t;
        // energy: 4 floats -> one float4, unit-stride across lanes (1KB/wave)
        *(f4v*)(e_out + 4 * t4) = mk4(o0.e, o1.e, o2.e, o3.e);
        // forces: 8 floats -> two float4
        *(f4v*)(f_out + 8 * t4)     = mk4(o0.fx, o0.fy, o1.fx, o1.fy);
        *(f4v*)(f_out + 8 * t4 + 4) = mk4(o2.fx, o2.fy, o3.fx, o3.fy);
        // energy_grad: 8 floats -> two float4
        *(f4v*)(g_out + 8 * t4)     = mk4(o0.gx, o0.gy, o1.gx, o1.gy);
        *(f4v*)(g_out + 8 * t4 + 4) = mk4(o2.gx, o2.gy, o3.gx, o3.gy);
        // hessian: 16 floats -> four float4
        *(f4v*)(h_out + 16 * t4)      = mk4(o0.hxx, BETA, BETA, o0.hyy);
        *(f4v*)(h_out + 16 * t4 + 4)  = mk4(o1.hxx, BETA, BETA, o1.hyy);
        *(f4v*)(h_out + 16 * t4 + 8)  = mk4(o2.hxx, BETA, BETA, o2.hyy);
        *(f4v*)(h_out + 16 * t4 + 12) = mk4(o3.hxx, BETA, BETA, o3.hyy);
        // eigenvalues: 4 + 4 floats -> one float4 each
        *(f4v*)(l0_out + 4 * t4) = mk4(o0.l0, o1.l0, o2.l0, o3.l0);
        *(f4v*)(l1_out + 4 * t4) = mk4(o0.l1, o1.l1, o2.l1, o3.l1);
    }

    // Tail: points [4*nq, n). B = 4194304 is divisible by 4; kept for safety.
    int base = nq << 2;
    int rem = n - base;
    if (rem > 0 && blockIdx.x == 0 && (int)threadIdx.x < rem) {
        int j = base + (int)threadIdx.x;
        const float* inf = (const float*)in4;
        PointOut o = compute_point(inf[2 * (size_t)j], inf[2 * (size_t)j + 1]);
        e_out[j] = o.e;
        f_out[2 * (size_t)j] = o.fx;  f_out[2 * (size_t)j + 1] = o.fy;
        g_out[2 * (size_t)j] = o.gx;  g_out[2 * (size_t)j + 1] = o.gy;
        h_out[4 * (size_t)j] = o.hxx; h_out[4 * (size_t)j + 1] = BETA;
        h_out[4 * (size_t)j + 2] = BETA; h_out[4 * (size_t)j + 3] = o.hyy;
        l0_out[j] = o.l0;
        l1_out[j] = o.l1;
    }
}

extern "C" void kernel_launch(void* const* d_in, const int* in_sizes, int n_in,
                              void* d_out, int out_size, void* d_ws, size_t ws_size,
                              hipStream_t stream) {
    const f4v* in4 = (const f4v*)d_in[0];
    float* out = (float*)d_out;
    int n = in_sizes[0] / 2;   // B points, each (x, y)

    int nq = n >> 2;
    int block = 256;
    int grid = (nq + block - 1) / block;
    if (grid < 1) grid = 1;
    fw_energy_gad_kernel<<<grid, block, 0, stream>>>(in4, out, n);
}

// Round 3
// 198.198 us; speedup vs baseline: 1.0508x; 1.0398x over previous
//
#include <hip/hip_runtime.h>

// FWEnergyGAD: element-wise double-well energy + forces + GAD direction +
// 2x2 Hessian eigendecomposition (closed form).
//
// Outputs concatenated flat in return order (n = B):
//   [0,     n)   energy
//   [n,    3n)   forces      (B,2)
//   [3n,   5n)   energy_grad (B,2)
//   [5n,   9n)   hessian     (B,2,2)
//   [9n,  10n)   eigenval 0  (smaller)
//   [10n, 11n)   eigenval 1  (larger)
//
// v4 = v1 memory structure (known best: 1 pt/thread, 16K blocks, plain
// cached stores, all line-complete unit-stride) + native-approx math.
// History: v2 (split-half + NT) and v3 (adjacent-quad 4pt/thread) both
// regressed ~8% -> store burst size / per-wave stream count are NOT the
// lever; thread count / occupancy correlates with goodness. So: revert
// structure, trim the serial ALU chain instead:
//   - sqrtf -> __builtin_amdgcn_sqrtf (v_sqrt_f32, 1 ULP; IEEE expansion
//     sequences removed). Reference eigenvalues come from jnp.linalg.eigh
//     (different algorithm, ~1e-6 rel difference already tolerated), so
//     1-ULP is far inside demonstrated slack.
//   - divisions -> v_rcp_f32 multiplies.
//   - gmag<1 -> g2<1 (compare squares); normalize via v_rsq_f32(g2);
//     clamp g2 at 1e-60 == reference's max(gmag,1e-30) guard.
//   - __launch_bounds__(256,8): pin 8 waves/SIMD.

typedef float f2v __attribute__((ext_vector_type(2)));
typedef float f4v __attribute__((ext_vector_type(4)));

__global__ __launch_bounds__(256, 8) void fw_energy_gad_kernel(
    const f2v* __restrict__ in, float* __restrict__ out, int n) {
    int i = blockIdx.x * blockDim.x + threadIdx.x;
    if (i >= n) return;

    const float BETA = 0.1f;

    f2v p = in[i];
    float u = p.x - 0.5f;
    float v = p.y - 0.5f;
    float uu = u * u;
    float vv = v * v;
    float a = uu - 1.0f;   // u^2 - 1
    float b = vv - 1.0f;   // v^2 - 1

    float energy = a * a + b * b + BETA * u * v;

    float gx = 4.0f * u * a + BETA * v;
    float gy = 4.0f * v * b + BETA * u;
    float fx = -gx;
    float fy = -gy;

    float hxx = 12.0f * uu - 4.0f;
    float hyy = 12.0f * vv - 4.0f;
    // hxy = BETA (constant)

    // 2x2 symmetric eigendecomposition, closed form.
    float d = 0.5f * (hxx - hyy);
    float m = 0.5f * (hxx + hyy);
    float r = __builtin_amdgcn_sqrtf(d * d + BETA * BETA);  // r >= 0.1
    float l0 = m - r;                        // smaller eigenvalue
    float l1 = m + r;                        // larger eigenvalue

    // Eigenvector of l0, branch chosen to avoid cancellation (|d| can be
    // ~380 vs hxy=0.1; the wrong branch computes r-|d|: catastrophic).
    bool pos = (d >= 0.0f);
    float wx = pos ? BETA : (d - r);
    float wy = pos ? -(d + r) : BETA;
    float n2 = wx * wx + wy * wy;            // >= 0.01

    // gad = -f + 2 (f.w_hat) w_hat ; sign of w irrelevant (quadratic).
    float fd = fx * wx + fy * wy;
    float s = (2.0f * fd) * __builtin_amdgcn_rcpf(n2);
    float gadx = -fx + s * wx;
    float gady = -fy + s * wy;

    float prod = l0 * l1;                    // matches reference's product
    float g2 = gadx * gadx + gady * gady;    // gmag^2; gmag<1 <=> g2<1
    if (prod > 0.0f && g2 < 1.0f) {
        float inv = __builtin_amdgcn_rsqf(fmaxf(g2, 1e-60f));
        gadx *= inv;
        gady *= inv;
    }
    // TAU = 1.0 -> energy_grad == gad

    size_t N = (size_t)n;
    float* e_out  = out;
    f2v*   f_out  = (f2v*)(out + N);
    f2v*   g_out  = (f2v*)(out + 3 * N);
    f4v*   h_out  = (f4v*)(out + 5 * N);
    float* l0_out = out + 9 * N;
    float* l1_out = out + 10 * N;

    e_out[i] = energy;
    f2v fo; fo.x = fx; fo.y = fy;
    f_out[i] = fo;
    f2v go; go.x = gadx; go.y = gady;
    g_out[i] = go;
    f4v ho; ho.x = hxx; ho.y = BETA; ho.z = BETA; ho.w = hyy;
    h_out[i] = ho;
    l0_out[i] = l0;
    l1_out[i] = l1;
}

extern "C" void kernel_launch(void* const* d_in, const int* in_sizes, int n_in,
                              void* d_out, int out_size, void* d_ws, size_t ws_size,
                              hipStream_t stream) {
    const f2v* in = (const f2v*)d_in[0];
    float* out = (float*)d_out;
    int n = in_sizes[0] / 2;   // B elements, each (x, y)

    int block = 256;
    int grid = (n + block - 1) / block;
    fw_energy_gad_kernel<<<grid, block, 0, stream>>>(in, out, n);
}